// Round 14
// baseline (321.358 us; speedup 1.0000x reference)
//
#include <hip/hip_runtime.h>

// CentroidPool: N=65536 x K=4096 x D=128 fp32 -> argmin_k ||x - c_k|| (int32).
// Stage 1: f16x3-split MFMA GEMM on mfma_f32_32x32x16_f16 (2382 TF rate, half
//   the MFMA instrs of 16x16x32). Wave tile = 32 rows x 64 cents/tile, 32
//   tiles (2048 cents); waves pair-split rows and K. B pre-packed in fragment
//   order -> every load 64x16B coalesced, offB advances uniformly (+1024).
//   Top-2 via sortable packed keys (score bits | kn6), 4 VALU ops/slot.
// Stage 2: exact fp64 rescore of the 2 candidates, 16 lanes/point.
// Layouts (m74/m101): C/D col=lane&31, row=(r&3)+8(r>>2)+4(lane>>5);
//   A[m=lane&31][k=(lane>>5)*8+j]; B[k=(lane>>5)*8+j][n=lane&31].

typedef _Float16 f16;
typedef f16  f16x8  __attribute__((ext_vector_type(8)));
typedef float f32x16 __attribute__((ext_vector_type(16)));

constexpr int N_PTS  = 65536;
constexpr int K_CENT = 4096;
constexpr int D_DIM  = 128;
constexpr int MB     = 64;     // points per block
constexpr float SOFF = 256.0f; // score offset => strictly positive scores

// ---------------------------------------------------------------------------
__global__ __launch_bounds__(256) void c2_kernel(const float* __restrict__ coords,
                                                 float* __restrict__ c2b) {
    int k = blockIdx.x * 256 + threadIdx.x;
    const float* c = coords + (size_t)k * D_DIM;
    float s = 0.f;
#pragma unroll
    for (int d = 0; d < D_DIM; ++d) s = fmaf(c[d], c[d], s);
    c2b[k] = s + SOFF;
}

// ---------------------------------------------------------------------------
// Pack coords into 32x32x16 B-fragment order, f16 hi/lo:
// unit u = (gt64*8 + ks)*2 + n ; dst = u*512 + lane*8 + j
//   cent = gt64*64 + n*32 + (lane&31), dim = ks*16 + (lane>>5)*8 + j.
// ---------------------------------------------------------------------------
__global__ __launch_bounds__(256) void split_pack(const float* __restrict__ c,
                                                  f16* __restrict__ chp,
                                                  f16* __restrict__ clp) {
    int e = blockIdx.x * 256 + threadIdx.x;   // K*D elements
    int cent = e >> 7, dim = e & 127;
    float x = c[e];
    f16 h = (f16)x;
    f16 l = (f16)(x - (float)h);
    int gt = cent >> 6, n = (cent >> 5) & 1, n31 = cent & 31;
    int ks = dim >> 4, hf = (dim >> 3) & 1, j = dim & 7;
    int lane = hf * 32 + n31;
    int dst = ((gt * 8 + ks) * 2 + n) * 512 + lane * 8 + j;
    chp[dst] = h;
    clp[dst] = l;
}

// ---------------------------------------------------------------------------
// Stage 1. Block = 4 waves x 64 points. Wave w: rows (w&1)*32..+32, cents
// (w>>1)*2048..+2048 in 32 tiles of 64 (2 n-groups of 32).
// latent (-2x) split h/l in XOR-swizzled LDS (row-major 128 f16, 16B col ^
// row&15). key = (bits(score)&~63)|kn6, kn6 = kt*2+n;
// cent = wv2*2048 + kt*64 + n*32 + (lane&31).
// ---------------------------------------------------------------------------
__global__ __launch_bounds__(256, 2) void argmin_mfma(
        const float* __restrict__ latent,
        const f16*   __restrict__ chp,
        const f16*   __restrict__ clp,
        const float* __restrict__ c2b,
        int* __restrict__ top1,
        int* __restrict__ top2) {
    __shared__ f16 latH[MB * 128];
    __shared__ f16 latL[MB * 128];
    __shared__ unsigned r1K[2][MB]; __shared__ int r1I[2][MB];
    __shared__ unsigned r2K[2][MB]; __shared__ int r2I[2][MB];

    const int t    = threadIdx.x;
    const int wave = t >> 6;
    const int lane = t & 63;
    const int n31  = lane & 31;
    const int hf   = lane >> 5;
    const int l15  = lane & 15;
    const int rowoff = (wave & 1) * 32;   // this wave's row group
    const int wv2    = wave >> 1;         // this wave's K half
    const int row0 = blockIdx.x * MB;

    {   // Stage latent: scale -2, split h/l, XOR-swizzle 16-B units.
        const float4* src = (const float4*)(latent + (size_t)row0 * D_DIM);
#pragma unroll
        for (int i = 0; i < 4; ++i) {
            int g  = i * 256 + t;          // float8 index in [0,1024)
            int r  = g >> 4;               // row
            int c8 = g & 15;               // logical 16-B column
            float4 v0 = src[2 * g];
            float4 v1 = src[2 * g + 1];
            float xs[8] = {v0.x, v0.y, v0.z, v0.w, v1.x, v1.y, v1.z, v1.w};
            f16x8 hv, lv;
#pragma unroll
            for (int c = 0; c < 8; ++c) {
                float x = -2.0f * xs[c];
                f16 h = (f16)x;
                hv[c] = h;
                lv[c] = (f16)(x - (float)h);
            }
            int pc = ((c8 ^ (r & 15)) << 3);
            *(f16x8*)&latH[r * 128 + pc] = hv;
            *(f16x8*)&latL[r * 128 + pc] = lv;
        }
    }
    __syncthreads();

    unsigned b1[32], b2[32];
#pragma unroll
    for (int i = 0; i < 32; ++i) { b1[i] = 0xFFFFFFFFu; b2[i] = 0xFFFFFFFFu; }

    const int cb0 = wv2 * 2048;                 // wave's first centroid
    const int abase = (rowoff + n31) * 128;     // A-row base in LDS
    unsigned offB = (unsigned)(wv2 * 512) * 512u + (unsigned)(lane * 8);

    // Named ping-pong regs — never address-taken.
    f16x8 Bah0, Bal0, Bah1, Bal1, Bbh0, Bbl0, Bbh1, Bbl1;
    f32x16 a0, a1;

#define PFB(P) \
    P##h0 = *(const f16x8*)(chp + offB); \
    P##l0 = *(const f16x8*)(clp + offB); \
    P##h1 = *(const f16x8*)(chp + offB + 512); \
    P##l1 = *(const f16x8*)(clp + offB + 512); \
    offB += 1024;

#define MF(d, a, b) d = __builtin_amdgcn_mfma_f32_32x32x16_f16(a, b, d, 0, 0, 0);

#define STEP(P, ks) { \
    const int pc_ = ((((ks) * 2) + hf) ^ l15) << 3; \
    f16x8 ah_ = *(const f16x8*)&latH[abase + pc_]; \
    f16x8 al_ = *(const f16x8*)&latL[abase + pc_]; \
    MF(a0, ah_, P##h0) MF(a0, ah_, P##l0) MF(a0, al_, P##h0) \
    MF(a1, ah_, P##h1) MF(a1, ah_, P##l1) MF(a1, al_, P##h1) }

#define INS1(s, kn, slot) { \
    unsigned key_ = (__float_as_uint(s) & 0xFFFFFFC0u) | (kn); \
    unsigned hi_ = key_ > b1[slot] ? key_ : b1[slot]; \
    b1[slot] = key_ < b1[slot] ? key_ : b1[slot]; \
    b2[slot] = hi_  < b2[slot] ? hi_  : b2[slot]; }

#define INS16(v, kn, base) \
    INS1(v[0],(kn),(base)+0)  INS1(v[1],(kn),(base)+1)  INS1(v[2],(kn),(base)+2)  INS1(v[3],(kn),(base)+3) \
    INS1(v[4],(kn),(base)+4)  INS1(v[5],(kn),(base)+5)  INS1(v[6],(kn),(base)+6)  INS1(v[7],(kn),(base)+7) \
    INS1(v[8],(kn),(base)+8)  INS1(v[9],(kn),(base)+9)  INS1(v[10],(kn),(base)+10) INS1(v[11],(kn),(base)+11) \
    INS1(v[12],(kn),(base)+12) INS1(v[13],(kn),(base)+13) INS1(v[14],(kn),(base)+14) INS1(v[15],(kn),(base)+15)

#define SPLAT16(x) {x,x,x,x,x,x,x,x,x,x,x,x,x,x,x,x}

    // Prime: load (kt=0, ks=0).
    PFB(Ba)
    float cv0 = c2b[cb0 + n31];
    float cv1 = c2b[cb0 + 32 + n31];

#pragma unroll 1
    for (int kt = 0; kt < 32; ++kt) {
        a0 = (f32x16)SPLAT16(cv0);
        a1 = (f32x16)SPLAT16(cv1);

        int ktn = (kt + 1) & 31;   // wraps at end; value then unused
        float cvn0 = c2b[cb0 + ktn * 64 + n31];
        float cvn1 = c2b[cb0 + ktn * 64 + 32 + n31];

        PFB(Bb) STEP(Ba, 0)  PFB(Ba) STEP(Bb, 1)
        PFB(Bb) STEP(Ba, 2)  PFB(Ba) STEP(Bb, 3)
        PFB(Bb) STEP(Ba, 4)  PFB(Ba) STEP(Bb, 5)
        PFB(Bb) STEP(Ba, 6)  PFB(Ba) STEP(Bb, 7)
        // NOTE: final PFB of the last tile over-reads <=1 KB past chp/clp into
        // the adjacent ws arrays (allocated, values unused).

        const unsigned kn0 = (unsigned)(kt * 2);
        INS16(a0, kn0, 0) INS16(a1, kn0 + 1u, 16)

        cv0 = cvn0; cv1 = cvn1;
    }

    // ---- Reduce: per slot pair (same row, two n-halves) merge, then 32-lane
    // butterfly (masks 1..16 stay within each half), (key,idx) lexicographic.
#pragma unroll
    for (int r = 0; r < 16; ++r) {
        unsigned k1 = b1[r],      k2 = b2[r];
        unsigned c1 = b1[r + 16], c2v = b2[r + 16];
#define RECON(k) (cb0 + (int)(((k) & 63u) >> 1) * 64 + (int)((k) & 1u) * 32 + n31)
        int i1 = RECON(k1), i2 = RECON(k2);
        int ci1 = RECON(c1), ci2 = RECON(c2v);
#undef RECON
        // merge two sorted-2 lists (in-lane): same-lane keys differ in kn6.
        {
            bool ow = c1 < k1;
            unsigned w1 = ow ? c1 : k1;  int w1i = ow ? ci1 : i1;
            unsigned ls = ow ? k1 : c1;  int lsi = ow ? i1 : ci1;
            unsigned ws = ow ? c2v : k2; int wsi = ow ? ci2 : i2;
            bool sw = ls < ws;
            k1 = w1; i1 = w1i;
            k2 = sw ? ls : ws; i2 = sw ? lsi : wsi;
        }
#pragma unroll
        for (int msk = 1; msk < 32; msk <<= 1) {
            unsigned ok1 = (unsigned)__shfl_xor((int)k1, msk, 64);
            int      oi1 = __shfl_xor(i1, msk, 64);
            unsigned ok2 = (unsigned)__shfl_xor((int)k2, msk, 64);
            int      oi2 = __shfl_xor(i2, msk, 64);
            bool ow = (ok1 < k1) || (ok1 == k1 && oi1 < i1);
            unsigned w1 = ow ? ok1 : k1; int w1i = ow ? oi1 : i1;
            unsigned ls = ow ? k1 : ok1; int lsi = ow ? i1 : oi1;
            unsigned ws = ow ? ok2 : k2; int wsi = ow ? oi2 : i2;
            bool sw = (ls < ws) || (ls == ws && lsi < wsi);
            k1 = w1; i1 = w1i;
            k2 = sw ? ls : ws; i2 = sw ? lsi : wsi;
        }
        if (n31 == 0) {
            int row = rowoff + (r & 3) + 8 * (r >> 2) + 4 * hf;
            r1K[wv2][row] = k1; r1I[wv2][row] = i1;
            r2K[wv2][row] = k2; r2I[wv2][row] = i2;
        }
    }
    __syncthreads();

    if (t < MB) {
        unsigned k1 = r1K[0][t], k2 = r2K[0][t];
        int      i1 = r1I[0][t], i2 = r2I[0][t];
        unsigned ok1 = r1K[1][t], ok2 = r2K[1][t];
        int      oi1 = r1I[1][t], oi2 = r2I[1][t];
        bool ow = (ok1 < k1) || (ok1 == k1 && oi1 < i1);
        unsigned w1 = ow ? ok1 : k1; int w1i = ow ? oi1 : i1;
        unsigned ls = ow ? k1 : ok1; int lsi = ow ? i1 : oi1;
        unsigned ws = ow ? ok2 : k2; int wsi = ow ? oi2 : i2;
        bool sw = (ls < ws) || (ls == ws && lsi < wsi);
        top1[row0 + t] = w1i;
        top2[row0 + t] = sw ? lsi : wsi;
    }
}

// ---------------------------------------------------------------------------
// Stage 2: exact fp64 rescore, 16 lanes per point (8 dims/lane + shuffle
// reduce). True winner wins; idx tie -> smaller index.
// ---------------------------------------------------------------------------
__global__ __launch_bounds__(256) void rescore(const float* __restrict__ latent,
                                               const float* __restrict__ coords,
                                               const int* __restrict__ top1,
                                               const int* __restrict__ top2,
                                               int* __restrict__ out) {
    int t = threadIdx.x;
    int p = blockIdx.x * 16 + (t >> 4);
    int l = t & 15;
    int i1 = top1[p], i2 = top2[p];
    const float4* xp = (const float4*)(latent + (size_t)p * D_DIM + l * 8);
    const float4* ap = (const float4*)(coords + (size_t)i1 * D_DIM + l * 8);
    const float4* bp = (const float4*)(coords + (size_t)i2 * D_DIM + l * 8);
    float4 x0 = xp[0], x1 = xp[1];
    float4 a0 = ap[0], a1 = ap[1];
    float4 b0 = bp[0], b1 = bp[1];
    double d1 = 0.0, d2 = 0.0, e;
    e = (double)x0.x - (double)a0.x; d1 += e * e;
    e = (double)x0.y - (double)a0.y; d1 += e * e;
    e = (double)x0.z - (double)a0.z; d1 += e * e;
    e = (double)x0.w - (double)a0.w; d1 += e * e;
    e = (double)x1.x - (double)a1.x; d1 += e * e;
    e = (double)x1.y - (double)a1.y; d1 += e * e;
    e = (double)x1.z - (double)a1.z; d1 += e * e;
    e = (double)x1.w - (double)a1.w; d1 += e * e;
    e = (double)x0.x - (double)b0.x; d2 += e * e;
    e = (double)x0.y - (double)b0.y; d2 += e * e;
    e = (double)x0.z - (double)b0.z; d2 += e * e;
    e = (double)x0.w - (double)b0.w; d2 += e * e;
    e = (double)x1.x - (double)b1.x; d2 += e * e;
    e = (double)x1.y - (double)b1.y; d2 += e * e;
    e = (double)x1.z - (double)b1.z; d2 += e * e;
    e = (double)x1.w - (double)b1.w; d2 += e * e;
#pragma unroll
    for (int msk = 1; msk < 16; msk <<= 1) {
        d1 += __shfl_xor(d1, msk, 16);
        d2 += __shfl_xor(d2, msk, 16);
    }
    if (l == 0) {
        bool second = (d2 < d1) || (d2 == d1 && i2 < i1);
        out[p] = second ? i2 : i1;
    }
}

// ---------------------------------------------------------------------------
extern "C" void kernel_launch(void* const* d_in, const int* in_sizes, int n_in,
                              void* d_out, int out_size, void* d_ws, size_t ws_size,
                              hipStream_t stream) {
    const float* latent = (const float*)d_in[0];
    const float* coords = (const float*)d_in[1];
    int* out = (int*)d_out;

    // ws: chp [K*D] f16 | clp [K*D] f16 | c2b [K] f32 | top1 [N] | top2 [N]
    f16*   chp = (f16*)d_ws;
    f16*   clp = chp + (size_t)K_CENT * D_DIM;
    float* c2b = (float*)(clp + (size_t)K_CENT * D_DIM);
    int*   t1  = (int*)(c2b + K_CENT);
    int*   t2  = t1 + N_PTS;

    c2_kernel<<<dim3(K_CENT / 256), dim3(256), 0, stream>>>(coords, c2b);
    split_pack<<<dim3(K_CENT * D_DIM / 256), dim3(256), 0, stream>>>(coords, chp, clp);
    argmin_mfma<<<dim3(N_PTS / MB), dim3(256), 0, stream>>>(latent, chp, clp, c2b, t1, t2);
    rescore<<<dim3(N_PTS / 16), dim3(256), 0, stream>>>(latent, coords, t1, t2, out);
}

// Round 15
// 253.260 us; speedup vs baseline: 1.2689x; 1.2689x over previous
//
#include <hip/hip_runtime.h>

// CentroidPool: N=65536 x K=4096 x D=128 fp32 -> argmin_k ||x - c_k|| (int32).
// Round-15 = round-13 core (175 us, MfmaUtil 55%) + launch-count surgery:
//   total-argmin was ~60 us in BOTH r13 and r14 regardless of rescore impl ->
//   per-dispatch overhead. Now 2 dispatches: prep (split_pack + c2 fused) and
//   argmin_mfma with the fp64 rescore fused into the block epilogue.
// r14 lesson (MfmaUtil 54.8->34.7): 32x32x16 with only 2 chained f32x16 accs
//   stalls on MFMA dependency latency — keep 16x16x32 with 16 indep f32x4 accs.
// Stage-1 math: f16x3-split GEMM (xh*ch + xh*cl + xl*ch, fp32 acc = c2 init),
//   top-2 via sortable packed keys (score bits | kn6), 4 VALU ops/slot,
//   register ping-pong B pipeline on fragment-order packed B (64x16B loads).

typedef _Float16 f16;
typedef f16  f16x8 __attribute__((ext_vector_type(8)));
typedef float f32x4 __attribute__((ext_vector_type(4)));

constexpr int N_PTS  = 65536;
constexpr int K_CENT = 4096;
constexpr int D_DIM  = 128;
constexpr int MB     = 64;     // points per block (4 waves share them)
constexpr int KW     = 1024;   // centroids per wave (waves split K 4-ways)
constexpr float SOFF = 256.0f; // score offset => strictly positive scores

// ---------------------------------------------------------------------------
// Prep (fused): blocks [0,2048) pack coords into f16 h/l fragment order
// (dst = ((gt*4+ds)*2+n)*512 + lane*8 + j); blocks [2048,2064) compute
// c2b[k] = |c_k|^2 + SOFF.
// ---------------------------------------------------------------------------
__global__ __launch_bounds__(256) void prep(const float* __restrict__ c,
                                            f16* __restrict__ chp,
                                            f16* __restrict__ clp,
                                            float* __restrict__ c2b) {
    int b = blockIdx.x;
    if (b < (K_CENT * D_DIM) / 256) {
        int e = b * 256 + threadIdx.x;    // K*D source elements
        int cent = e >> 7, dim = e & 127;
        float x = c[e];
        f16 h = (f16)x;
        f16 l = (f16)(x - (float)h);
        int gt = cent >> 5, n = (cent >> 4) & 1, l15 = cent & 15;
        int ds = dim >> 5, quad = (dim >> 3) & 3, j = dim & 7;
        int lane = quad * 16 + l15;
        int dst = ((gt * 4 + ds) * 2 + n) * 512 + lane * 8 + j;
        chp[dst] = h;
        clp[dst] = l;
    } else {
        int k = (b - (K_CENT * D_DIM) / 256) * 256 + threadIdx.x;
        const float* cr = c + (size_t)k * D_DIM;
        float s = 0.f;
#pragma unroll
        for (int d = 0; d < D_DIM; ++d) s = fmaf(cr[d], cr[d], s);
        c2b[k] = s + SOFF;
    }
}

// ---------------------------------------------------------------------------
// Main kernel. Block = 4 waves x 64 points; latent (-2x) split h/l in
// XOR-swizzled LDS. Wave w scans cents [w*1024,(w+1)*1024) in 32-wide k-tiles
// (2 n-groups). Ping-pong invariant at tile top: Ba = (kt, ds0), offB ->
// (kt, ds1). key = (bits(score)&~63)|kn, kn = kt*2+n (6b);
// cent = (wave*64+kn)*16 + l15. Tail: in-block fp64 rescore of top-2.
// ---------------------------------------------------------------------------
__global__ __launch_bounds__(256, 2) void argmin_mfma(
        const float* __restrict__ latent,
        const float* __restrict__ coords,
        const f16*   __restrict__ chp,
        const f16*   __restrict__ clp,
        const float* __restrict__ c2b,
        int* __restrict__ out) {
    __shared__ f16 latH[MB * 128];
    __shared__ f16 latL[MB * 128];
    __shared__ unsigned r1K[4][MB]; __shared__ int r1I[4][MB];
    __shared__ unsigned r2K[4][MB]; __shared__ int r2I[4][MB];
    __shared__ int fin1[MB]; __shared__ int fin2[MB];

    const int t    = threadIdx.x;
    const int wave = t >> 6;
    const int lane = t & 63;
    const int quad = lane >> 4;
    const int l15  = lane & 15;
    const int row0 = blockIdx.x * MB;

    {   // Stage latent: scale -2, split h/l, XOR-swizzle 16-B units.
        const float4* src = (const float4*)(latent + (size_t)row0 * D_DIM);
#pragma unroll
        for (int i = 0; i < 4; ++i) {
            int g  = i * 256 + t;          // float8 index in [0,1024)
            int r  = g >> 4;               // row (16 float8 per row)
            int c8 = g & 15;               // logical 16-B column
            float4 v0 = src[2 * g];
            float4 v1 = src[2 * g + 1];
            float xs[8] = {v0.x, v0.y, v0.z, v0.w, v1.x, v1.y, v1.z, v1.w};
            f16x8 hv, lv;
#pragma unroll
            for (int c = 0; c < 8; ++c) {
                float x = -2.0f * xs[c];
                f16 h = (f16)x;
                hv[c] = h;
                lv[c] = (f16)(x - (float)h);
            }
            int pc = ((c8 ^ (r & 15)) << 3);
            *(f16x8*)&latH[r * 128 + pc] = hv;
            *(f16x8*)&latL[r * 128 + pc] = lv;
        }
    }
    __syncthreads();

    unsigned b1[16], b2[16];
#pragma unroll
    for (int i = 0; i < 16; ++i) { b1[i] = 0xFFFFFFFFu; b2[i] = 0xFFFFFFFFu; }

    const int wbase = wave * KW;
    // Packed-B element offset of the next step's load: uniform +1024/step.
    unsigned offB = (unsigned)(wave * 32 * 4) * 1024u + (unsigned)(lane * 8);

    // Named ping-pong regs — never address-taken.
    f16x8 Ba0, Ba1, Ba2, Ba3, Bb0, Bb1, Bb2, Bb3;
    f32x4 a00, a01, a10, a11, a20, a21, a30, a31;

#define PFB(P) \
    P##0 = *(const f16x8*)(chp + offB); \
    P##1 = *(const f16x8*)(clp + offB); \
    P##2 = *(const f16x8*)(chp + offB + 512); \
    P##3 = *(const f16x8*)(clp + offB + 512);

#define MF(d, a, b) d = __builtin_amdgcn_mfma_f32_16x16x32_f16(a, b, d, 0, 0, 0);

#define STEP(P, ds) { \
    const int pc_ = ((((ds) << 2) + quad) ^ l15) << 3; \
    f16x8 ah_, al_; \
    ah_ = *(const f16x8*)&latH[(     l15) * 128 + pc_]; \
    al_ = *(const f16x8*)&latL[(     l15) * 128 + pc_]; \
    MF(a00, ah_, P##0) MF(a00, ah_, P##1) MF(a00, al_, P##0) \
    MF(a01, ah_, P##2) MF(a01, ah_, P##3) MF(a01, al_, P##2) \
    ah_ = *(const f16x8*)&latH[(16 + l15) * 128 + pc_]; \
    al_ = *(const f16x8*)&latL[(16 + l15) * 128 + pc_]; \
    MF(a10, ah_, P##0) MF(a10, ah_, P##1) MF(a10, al_, P##0) \
    MF(a11, ah_, P##2) MF(a11, ah_, P##3) MF(a11, al_, P##2) \
    ah_ = *(const f16x8*)&latH[(32 + l15) * 128 + pc_]; \
    al_ = *(const f16x8*)&latL[(32 + l15) * 128 + pc_]; \
    MF(a20, ah_, P##0) MF(a20, ah_, P##1) MF(a20, al_, P##0) \
    MF(a21, ah_, P##2) MF(a21, ah_, P##3) MF(a21, al_, P##2) \
    ah_ = *(const f16x8*)&latH[(48 + l15) * 128 + pc_]; \
    al_ = *(const f16x8*)&latL[(48 + l15) * 128 + pc_]; \
    MF(a30, ah_, P##0) MF(a30, ah_, P##1) MF(a30, al_, P##0) \
    MF(a31, ah_, P##2) MF(a31, ah_, P##3) MF(a31, al_, P##2) }

#define INS1(s, kn, slot) { \
    unsigned key_ = (__float_as_uint(s) & 0xFFFFFFC0u) | (kn); \
    unsigned hi_ = key_ > b1[slot] ? key_ : b1[slot]; \
    b1[slot] = key_ < b1[slot] ? key_ : b1[slot]; \
    b2[slot] = hi_  < b2[slot] ? hi_  : b2[slot]; }

#define INS4(av, kn, m) \
    INS1(av[0], kn, (m) * 4 + 0) INS1(av[1], kn, (m) * 4 + 1) \
    INS1(av[2], kn, (m) * 4 + 2) INS1(av[3], kn, (m) * 4 + 3)

    // Prime: load (kt=0, ds=0) into Ba; offB -> (0, ds1).
    PFB(Ba)
    offB += 1024;
    float cv0 = c2b[wbase + l15];
    float cv1 = c2b[wbase + 16 + l15];

#pragma unroll 1
    for (int kt = 0; kt < KW / 32; ++kt) {
        a00 = (f32x4){cv0, cv0, cv0, cv0}; a01 = (f32x4){cv1, cv1, cv1, cv1};
        a10 = a00; a11 = a01; a20 = a00; a21 = a01; a30 = a00; a31 = a01;

        int ktn = (kt + 1) & 31;    // wraps at end; value then unused
        float cvn0 = c2b[wbase + ktn * 32 + l15];
        float cvn1 = c2b[wbase + ktn * 32 + 16 + l15];

        PFB(Bb) offB += 1024; STEP(Ba, 0)   // loads (kt,ds1)
        PFB(Ba) offB += 1024; STEP(Bb, 1)   // loads (kt,ds2)
        PFB(Bb) offB += 1024; STEP(Ba, 2)   // loads (kt,ds3); offB -> (kt+1,ds0)
        if (kt != KW / 32 - 1) { PFB(Ba) }  // loads (kt+1,ds0)
        offB += 1024;                       // -> (kt+1,ds1)
        STEP(Bb, 3)

        const unsigned kn0 = (unsigned)(kt * 2);
        const unsigned kn1 = kn0 + 1u;
        INS4(a00, kn0, 0) INS4(a10, kn0, 1) INS4(a20, kn0, 2) INS4(a30, kn0, 3)
        INS4(a01, kn1, 0) INS4(a11, kn1, 1) INS4(a21, kn1, 2) INS4(a31, kn1, 3)

        cv0 = cvn0; cv1 = cvn1;
    }

    // Quad butterfly: merge two sorted-2 (key,idx) lists per step.
#pragma unroll
    for (int m = 0; m < 4; ++m)
#pragma unroll
        for (int r = 0; r < 4; ++r) {
            unsigned k1 = b1[m * 4 + r], k2 = b2[m * 4 + r];
            int i1 = ((wave * 64 + (int)(k1 & 63u)) << 4) | l15;
            int i2 = ((wave * 64 + (int)(k2 & 63u)) << 4) | l15;
#pragma unroll
            for (int msk = 1; msk < 16; msk <<= 1) {
                unsigned ok1 = (unsigned)__shfl_xor((int)k1, msk, 64);
                int      oi1 = __shfl_xor(i1, msk, 64);
                unsigned ok2 = (unsigned)__shfl_xor((int)k2, msk, 64);
                int      oi2 = __shfl_xor(i2, msk, 64);
                bool ow = ok1 < k1;
                unsigned w1k = ow ? ok1 : k1; int w1i = ow ? oi1 : i1;
                unsigned lsk = ow ? k1 : ok1; int lsi = ow ? i1 : oi1;
                unsigned wsk = ow ? ok2 : k2; int wsi = ow ? oi2 : i2;
                bool sw = lsk < wsk;
                k1 = w1k; i1 = w1i;
                k2 = sw ? lsk : wsk; i2 = sw ? lsi : wsi;
            }
            if (l15 == 0) {
                int p = m * 16 + quad * 4 + r;
                r1K[wave][p] = k1; r1I[wave][p] = i1;
                r2K[wave][p] = k2; r2I[wave][p] = i2;
            }
        }
    __syncthreads();

    if (t < MB) {
        unsigned k1 = r1K[0][t], k2 = r2K[0][t];
        int      i1 = r1I[0][t], i2 = r2I[0][t];
#pragma unroll
        for (int w = 1; w < 4; ++w) {
            unsigned ok1 = r1K[w][t], ok2 = r2K[w][t];
            int      oi1 = r1I[w][t], oi2 = r2I[w][t];
            bool ow = ok1 < k1;
            unsigned w1k = ow ? ok1 : k1; int w1i = ow ? oi1 : i1;
            unsigned lsk = ow ? k1 : ok1; int lsi = ow ? i1 : oi1;
            unsigned wsk = ow ? ok2 : k2; int wsi = ow ? oi2 : i2;
            bool sw = lsk < wsk;
            k1 = w1k; i1 = w1i;
            k2 = sw ? lsk : wsk; i2 = sw ? lsi : wsi;
        }
        fin1[t] = i1;
        fin2[t] = i2;
    }
    __syncthreads();

    // ---- Fused exact fp64 rescore: 4 lanes per point (32 dims each), shuffle
    // reduce; true winner wins (idx tie -> smaller index).
    {
        int p = t >> 2, j = t & 3;
        int i1 = fin1[p], i2 = fin2[p];
        const float4* xp = (const float4*)(latent + (size_t)(row0 + p) * D_DIM + j * 32);
        const float4* ap = (const float4*)(coords + (size_t)i1 * D_DIM + j * 32);
        const float4* bp = (const float4*)(coords + (size_t)i2 * D_DIM + j * 32);
        double d1 = 0.0, d2 = 0.0, e;
#pragma unroll
        for (int q = 0; q < 8; ++q) {
            float4 xv = xp[q], av = ap[q], bv = bp[q];
            e = (double)xv.x - (double)av.x; d1 += e * e;
            e = (double)xv.y - (double)av.y; d1 += e * e;
            e = (double)xv.z - (double)av.z; d1 += e * e;
            e = (double)xv.w - (double)av.w; d1 += e * e;
            e = (double)xv.x - (double)bv.x; d2 += e * e;
            e = (double)xv.y - (double)bv.y; d2 += e * e;
            e = (double)xv.z - (double)bv.z; d2 += e * e;
            e = (double)xv.w - (double)bv.w; d2 += e * e;
        }
        d1 += __shfl_xor(d1, 1, 64); d1 += __shfl_xor(d1, 2, 64);
        d2 += __shfl_xor(d2, 1, 64); d2 += __shfl_xor(d2, 2, 64);
        if (j == 0) {
            bool second = (d2 < d1) || (d2 == d1 && i2 < i1);
            out[row0 + p] = second ? i2 : i1;
        }
    }
}

// ---------------------------------------------------------------------------
extern "C" void kernel_launch(void* const* d_in, const int* in_sizes, int n_in,
                              void* d_out, int out_size, void* d_ws, size_t ws_size,
                              hipStream_t stream) {
    const float* latent = (const float*)d_in[0];
    const float* coords = (const float*)d_in[1];
    int* out = (int*)d_out;

    // ws: chp [K*D] f16 | clp [K*D] f16 | c2b [K] f32
    f16*   chp = (f16*)d_ws;
    f16*   clp = chp + (size_t)K_CENT * D_DIM;
    float* c2b = (float*)(clp + (size_t)K_CENT * D_DIM);

    prep<<<dim3((K_CENT * D_DIM) / 256 + K_CENT / 256), dim3(256), 0, stream>>>(
        coords, chp, clp, c2b);
    argmin_mfma<<<dim3(N_PTS / MB), dim3(256), 0, stream>>>(
        latent, coords, chp, clp, c2b, out);
}